// Round 6
// baseline (433.030 us; speedup 1.0000x reference)
//
#include <hip/hip_runtime.h>

typedef __attribute__((ext_vector_type(8))) short s16x8;
typedef __attribute__((ext_vector_type(4))) short s16x4;
typedef __attribute__((ext_vector_type(4))) float f32x4;
typedef __attribute__((ext_vector_type(16))) float f32x16;
typedef __attribute__((ext_vector_type(2))) unsigned uint2v;

#define DEVINL __device__ __forceinline__

// ---------- bf16 helpers ----------
DEVINL float b2f(short u){ return __uint_as_float(((unsigned)(unsigned short)u) << 16); }
DEVINL short f2bf(float f){
  unsigned u = __float_as_uint(f);
  u += 0x7fffu + ((u >> 16) & 1u);
  return (short)(u >> 16);
}
DEVINL unsigned cvtpk(float lo, float hi){
  unsigned r;
  asm("v_cvt_pk_bf16_f32 %0, %1, %2" : "=v"(r) : "v"(lo), "v"(hi));
  return r;
}
DEVINL float max3f(float a, float b, float c){
  float r; asm("v_max3_f32 %0, %1, %2, %3" : "=v"(r) : "v"(a), "v"(b), "v"(c)); return r;
}

#if __has_builtin(__builtin_amdgcn_exp2f)
#define EXP2F __builtin_amdgcn_exp2f
#else
#define EXP2F exp2f
#endif

// ---------- MFMA wrappers ----------
DEVINL f32x4 mfma32(s16x8 a, s16x8 b, f32x4 c){
  return __builtin_amdgcn_mfma_f32_16x16x32_bf16(a, b, c, 0, 0, 0);
}
DEVINL f32x16 mfma3216(s16x8 a, s16x8 b, f32x16 c){
  return __builtin_amdgcn_mfma_f32_32x32x16_bf16(a, b, c, 0, 0, 0);
}

DEVINL uint2v pl32swap(unsigned a, unsigned b){
#if __has_builtin(__builtin_amdgcn_permlane32_swap)
  return __builtin_amdgcn_permlane32_swap(a, b, false, false);
#else
  asm volatile("v_permlane32_swap_b32 %0, %1" : "+v"(a), "+v"(b));
  uint2v r; r[0] = a; r[1] = b; return r;
#endif
}

// ---------- async global->LDS (width 16) ----------
typedef const unsigned __attribute__((address_space(1)))* gas1;
typedef unsigned __attribute__((address_space(3)))* las3;
DEVINL void gload16(const short* g, short* l){
  __builtin_amdgcn_global_load_lds((gas1)g, (las3)l, 16, 0, 0);
}

// ---------- sync primitives ----------
#define CFENCE asm volatile("" ::: "memory")
#define PBAR  do{ CFENCE; __builtin_amdgcn_sched_barrier(0); __builtin_amdgcn_s_barrier(); \
                  __builtin_amdgcn_sched_barrier(0); CFENCE; }while(0)
#define VMW4 asm volatile("s_waitcnt vmcnt(4)" ::: "memory")
#define VMW3 asm volatile("s_waitcnt vmcnt(3)" ::: "memory")
#define VMW0 asm volatile("s_waitcnt vmcnt(0)" ::: "memory")
#define PRIO1 __builtin_amdgcn_s_setprio(1)
#define PRIO0 __builtin_amdgcn_s_setprio(0)

// ---------- problem constants ----------
static const int Bc   = 4;
static const int Nc   = 2048;
static const int DIM  = 1024;
static const int Tc   = Bc * Nc;      // 8192 tokens
static const int MLP  = 4096;
static const int D3   = 3072;

// ---------- ws layout (bytes) ----------
static const size_t OFF_XB    = 0;
static const size_t OFF_WQKVT = OFF_XB    + 16777216;
static const size_t OFF_W1T   = OFF_WQKVT + 6291456;
static const size_t OFF_W2T   = OFF_W1T   + 8388608;
static const size_t OFF_WOUTT = OFF_W2T   + 8388608;
static const size_t OFF_QKV   = OFF_WOUTT + 2097152;
static const size_t OFF_QLN   = OFF_QKV   + 50331648;
static const size_t OFF_KLN   = OFF_QLN   + 16777216;
static const size_t OFF_VT    = OFF_KLN   + 16777216;
static const size_t OFF_ATTNV = OFF_VT    + 16777216;
static const size_t OFF_H     = OFF_QKV;   // aliases of dead regions
static const size_t OFF_P2    = OFF_KLN;
static const size_t OFF_A2    = OFF_VT;

// ============================================================
// x fp32 -> bf16
// ============================================================
__global__ __launch_bounds__(256) void conv_x(const float* __restrict__ x, short* __restrict__ xb){
  size_t i = ((size_t)blockIdx.x * 256 + threadIdx.x) * 8;
  f32x4 v0 = *(const f32x4*)(x + i);
  f32x4 v1 = *(const f32x4*)(x + i + 4);
  s16x8 o;
#pragma unroll
  for (int j = 0; j < 4; ++j){ o[j] = f2bf(v0[j]); o[4+j] = f2bf(v1[j]); }
  *(s16x8*)(xb + i) = o;
}

// ============================================================
// W[K][N] fp32 -> Wt[N][K] bf16
// ============================================================
__global__ __launch_bounds__(256) void transpose_conv(const float* __restrict__ W, short* __restrict__ Wt,
                                                      int K, int N){
  __shared__ float tile[32][33];
  int ntx = N >> 5;
  int tx = blockIdx.x % ntx, ty = blockIdx.x / ntx;
  int r = threadIdx.x >> 3, c = (threadIdx.x & 7) * 4;
  f32x4 v = *(const f32x4*)(W + (size_t)(ty*32 + r)*N + tx*32 + c);
  tile[r][c] = v[0]; tile[r][c+1] = v[1]; tile[r][c+2] = v[2]; tile[r][c+3] = v[3];
  __syncthreads();
  s16x4 o;
#pragma unroll
  for (int j = 0; j < 4; ++j) o[j] = f2bf(tile[c+j][r]);
  *(s16x4*)(Wt + (size_t)(tx*32 + r)*K + ty*32 + c) = o;
}

// ============================================================
// Deep-pipelined GEMM. R6: each LDS slot is its OWN __shared__ array and the
// K-loop is unrolled 2 tiles/iter, so every global_load_lds target is a
// distinct IR object from every ds_read source in flight -> alias analysis
// proves disjointness -> no compiler-inserted vmcnt(0) before ds_reads; the
// counted VMW4/VMW3 at tile boundaries is the ONLY vmem wait (T3+T4).
// A slot (buf,kk[,mh]) = 128rows x 32cols (8KB); B slot (buf,kk) = 256x32 (16KB).
// k-group swizzle (R4, conflict-free): src col gsw, read col qsw8.
// ============================================================
template<int BM, int ACT>
__global__ __launch_bounds__(512, 2) void gemmDP(const short* __restrict__ A, const short* __restrict__ Bt,
                                                 short* __restrict__ C, const float* __restrict__ bias,
                                                 int M, int N, int K){
  constexpr int MREP = BM/32;
  __shared__ short sA0[4096], sA1[4096], sA2[4096], sA3[4096];
  __shared__ short sA4[(BM==256)?4096:4], sA5[(BM==256)?4096:4];
  __shared__ short sA6[(BM==256)?4096:4], sA7[(BM==256)?4096:4];
  __shared__ short sB0[8192], sB1[8192], sB2[8192], sB3[8192];

  const int tid = threadIdx.x;
  const int w = tid >> 6, lane = tid & 63;
  const int lr = lane & 15, g = lane >> 4;
  const int wr = w >> 2, wc = w & 3;
  const int NT = K >> 6;
  const int NIT = NT >> 1;

  const int nbn = N >> 8;
  const int cpx = gridDim.x >> 3;
  const int bid = (int)blockIdx.x;
  const int sw = (bid & 7)*cpx + (bid >> 3);
  const int bm = sw / nbn, bn = sw % nbn;

  const int l2 = lane >> 2;
  const int gsw = ((lane & 3) - ((lane >> 3) & 3)) & 3;
  const int cof = gsw * 8;
  const int qsw8 = ((g + (lr >> 1)) & 3) * 8;

  const size_t arow = (BM==256) ? (size_t)(bm*256 + (w>>2)*128 + (w&3)*16 + l2)
                                : (size_t)(bm*128 + w*16 + l2);
  const short* ap0 = A  + arow*K + cof;
  const short* bp0 = Bt + (size_t)(bn*256 + w*16 + l2)*K + cof;

// stage one 8KB A slot / one 16KB B slot (2 loads)
#define STA_(ARR, T, mh, kk) gload16(ap0 + (size_t)(mh)*64*K + (size_t)(T)*64 + (kk)*32, ARR + w*512)
#define STB_(ARR, T, kk) do{ gload16(bp0 + (size_t)(T)*64 + (kk)*32, ARR + w*512); \
                             gload16(bp0 + (size_t)128*K + (size_t)(T)*64 + (kk)*32, ARR + 4096 + w*512); }while(0)
#define LDA_(ARR, mi) (*(const s16x8*)&ARR[(wr*64 + (mi)*16 + lr)*32 + qsw8])
#define LDB_(ARR, ni) (*(const s16x8*)&ARR[(wc*64 + (ni)*16 + lr)*32 + qsw8])

  f32x4 acc[MREP][4] = {};

#define MMROW(ai, r) \
  acc[r][0]=mfma32(ai,b0,acc[r][0]); acc[r][1]=mfma32(ai,b1,acc[r][1]); \
  acc[r][2]=mfma32(ai,b2,acc[r][2]); acc[r][3]=mfma32(ai,b3,acc[r][3]);
#define RDA4(ARR) { a0=LDA_(ARR,0); a1=LDA_(ARR,1); a2=LDA_(ARR,2); a3=LDA_(ARR,3); }
#define RDB4(ARR) { b0=LDB_(ARR,0); b1=LDB_(ARR,1); b2=LDB_(ARR,2); b3=LDB_(ARR,3); }

  // ---- prologue: tile0 full + tile1 k0-half; counted drain of tile0 ----
  if constexpr (BM==256){
    STA_(sA0,0,0,0); STA_(sA1,0,1,0); STB_(sB0,0,0);   // t0 k0
    STA_(sA2,0,0,1); STA_(sA3,0,1,1); STB_(sB1,0,1);   // t0 k1
    STA_(sA4,1,0,0); STA_(sA5,1,1,0); STB_(sB2,1,0);   // t1 k0
    VMW4;            // leaves t1-k0's 4 in flight; t0 fully landed
  } else {
    STA_(sA0,0,0,0); STB_(sB0,0,0);                    // t0 k0
    STA_(sA1,0,0,1); STB_(sB1,0,1);                    // t0 k1
    STA_(sA2,1,0,0); STB_(sB2,1,0);                    // t1 k0
    VMW3;
  }
  PBAR;

  for (int i = 0; i < NIT; ++i){
    const int t = i << 1;
    const bool more = (t + 2 < NT);
    s16x8 a0,a1,a2,a3,b0,b1,b2,b3;

    if constexpr (BM==256){
      // p1: (t,k0,m0); stage t+1 k1 A -> sA6,sA7
      RDA4(sA0) RDB4(sB0)
      STA_(sA6, t+1, 0, 1); STA_(sA7, t+1, 1, 1);
      PBAR; PRIO1; MMROW(a0,0) MMROW(a1,1) MMROW(a2,2) MMROW(a3,3) PRIO0; PBAR;
      // p2: (t,k0,m1) reuse B; stage t+1 k1 B -> sB3
      RDA4(sA1)
      STB_(sB3, t+1, 1);
      PBAR; PRIO1; MMROW(a0,4) MMROW(a1,5) MMROW(a2,6) MMROW(a3,7) PRIO0; PBAR;
      // p3: (t,k1,m0); stage t+2 k0 A -> sA0,sA1
      RDA4(sA2) RDB4(sB1)
      if (more){ STA_(sA0, t+2, 0, 0); STA_(sA1, t+2, 1, 0); }
      PBAR; PRIO1; MMROW(a0,0) MMROW(a1,1) MMROW(a2,2) MMROW(a3,3) PRIO0; PBAR;
      // p4: (t,k1,m1); stage t+2 k0 B -> sB0; counted wait certifies t+1 k1
      RDA4(sA3)
      if (more){ STB_(sB0, t+2, 0); }
      PBAR; PRIO1; MMROW(a0,4) MMROW(a1,5) MMROW(a2,6) MMROW(a3,7) PRIO0;
      if (more){ VMW4; } else { VMW0; }
      PBAR;
      // p5: (t+1,k0,m0); stage t+2 k1 A -> sA2,sA3
      RDA4(sA4) RDB4(sB2)
      if (more){ STA_(sA2, t+2, 0, 1); STA_(sA3, t+2, 1, 1); }
      PBAR; PRIO1; MMROW(a0,0) MMROW(a1,1) MMROW(a2,2) MMROW(a3,3) PRIO0; PBAR;
      // p6: (t+1,k0,m1); stage t+2 k1 B -> sB1
      RDA4(sA5)
      if (more){ STB_(sB1, t+2, 1); }
      PBAR; PRIO1; MMROW(a0,4) MMROW(a1,5) MMROW(a2,6) MMROW(a3,7) PRIO0; PBAR;
      // p7: (t+1,k1,m0); stage t+3 k0 A -> sA4,sA5
      RDA4(sA6) RDB4(sB3)
      if (more){ STA_(sA4, t+3, 0, 0); STA_(sA5, t+3, 1, 0); }
      PBAR; PRIO1; MMROW(a0,0) MMROW(a1,1) MMROW(a2,2) MMROW(a3,3) PRIO0; PBAR;
      // p8: (t+1,k1,m1); stage t+3 k0 B -> sB2; counted wait certifies t+2 k1
      RDA4(sA7)
      if (more){ STB_(sB2, t+3, 0); }
      PBAR; PRIO1; MMROW(a0,4) MMROW(a1,5) MMROW(a2,6) MMROW(a3,7) PRIO0;
      if (more){ VMW4; }
      PBAR;
    } else {
      // p1: (t,k0); stage t+1 k1 -> sA3,sB3
      RDA4(sA0) RDB4(sB0)
      STA_(sA3, t+1, 0, 1); STB_(sB3, t+1, 1);
      PBAR; PRIO1; MMROW(a0,0) MMROW(a1,1) MMROW(a2,2) MMROW(a3,3) PRIO0; PBAR;
      // p2: (t,k1); stage t+2 k0 -> sA0,sB0; counted wait certifies t+1 k1
      RDA4(sA1) RDB4(sB1)
      if (more){ STA_(sA0, t+2, 0, 0); STB_(sB0, t+2, 0); }
      PBAR; PRIO1; MMROW(a0,0) MMROW(a1,1) MMROW(a2,2) MMROW(a3,3) PRIO0;
      if (more){ VMW3; } else { VMW0; }
      PBAR;
      // p3: (t+1,k0); stage t+2 k1 -> sA1,sB1
      RDA4(sA2) RDB4(sB2)
      if (more){ STA_(sA1, t+2, 0, 1); STB_(sB1, t+2, 1); }
      PBAR; PRIO1; MMROW(a0,0) MMROW(a1,1) MMROW(a2,2) MMROW(a3,3) PRIO0; PBAR;
      // p4: (t+1,k1); stage t+3 k0 -> sA2,sB2; counted wait certifies t+2 k1
      RDA4(sA3) RDB4(sB3)
      if (more){ STA_(sA2, t+3, 0, 0); STB_(sB2, t+3, 0); }
      PBAR; PRIO1; MMROW(a0,0) MMROW(a1,1) MMROW(a2,2) MMROW(a3,3) PRIO0;
      if (more){ VMW3; }
      PBAR;
    }
  }
#undef MMROW
#undef RDA4
#undef RDB4
#undef STA_
#undef STB_
#undef LDA_
#undef LDB_

  // ---- epilogue ----
#pragma unroll
  for (int ni = 0; ni < 4; ++ni){
    const int col = bn*256 + wc*64 + ni*16 + lr;
    const float bv = bias ? bias[col] : 0.f;
#pragma unroll
    for (int a = 0; a < MREP; ++a){
      const int row0 = bm*BM + wr*(BM/2) + a*16 + 4*g;
      f32x4 v = acc[a][ni];
#pragma unroll
      for (int i = 0; i < 4; ++i){
        float val = v[i] + bv;
        if constexpr (ACT) val = 0.5f*val*(1.f + erff(val*0.70710678118f));
        C[(size_t)(row0+i)*N + col] = f2bf(val);
      }
    }
  }
}

// ============================================================
// q/k LayerNorm (d=64) + head-reorg; v -> Vt [bh][d][n]
// ============================================================
__global__ __launch_bounds__(256) void ln_reorg(const short* __restrict__ qkv, short* __restrict__ qln,
                                                short* __restrict__ kln, short* __restrict__ vtb){
  __shared__ short vtile[64*72];
  int bh = blockIdx.x >> 5, tch = blockIdx.x & 31;
  int b = bh >> 4, h = bh & 15;
  int tq = threadIdx.x >> 2, j = threadIdx.x & 3;
  size_t row = (size_t)b*Nc + tch*64 + tq;
  const short* base = qkv + row*D3 + h*64 + j*16;
  size_t orow = ((size_t)bh*Nc + tch*64 + tq)*64 + j*16;

#pragma unroll
  for (int part = 0; part < 2; ++part){
    const short* src = base + part*DIM;
    s16x8 u0 = *(const s16x8*)src;
    s16x8 u1 = *(const s16x8*)(src + 8);
    float f[16]; float s = 0.f, sq = 0.f;
#pragma unroll
    for (int i = 0; i < 8; ++i){ f[i] = b2f(u0[i]); f[8+i] = b2f(u1[i]); }
#pragma unroll
    for (int i = 0; i < 16; ++i){ s += f[i]; sq += f[i]*f[i]; }
    s  += __shfl_xor(s, 1);  s  += __shfl_xor(s, 2);
    sq += __shfl_xor(sq, 1); sq += __shfl_xor(sq, 2);
    float mu = s * (1.f/64.f);
    float var = sq * (1.f/64.f) - mu*mu;
    float inv = rsqrtf(var + 1e-5f) * (part == 0 ? 0.04508422003f : 1.f);
    s16x8 o0, o1;
#pragma unroll
    for (int i = 0; i < 8; ++i){ o0[i] = f2bf((f[i]-mu)*inv); o1[i] = f2bf((f[8+i]-mu)*inv); }
    short* dst = (part == 0 ? qln : kln) + orow;
    *(s16x8*)dst = o0; *(s16x8*)(dst + 8) = o1;
  }

  s16x8 v0 = *(const s16x8*)(base + 2*DIM);
  s16x8 v1 = *(const s16x8*)(base + 2*DIM + 8);
  *(s16x8*)&vtile[tq*72 + j*16]     = v0;
  *(s16x8*)&vtile[tq*72 + j*16 + 8] = v1;
  __syncthreads();
  s16x8 o0, o1;
#pragma unroll
  for (int i = 0; i < 8; ++i){
    o0[i] = vtile[(j*16 + i)*72 + tq];
    o1[i] = vtile[(j*16 + 8 + i)*72 + tq];
  }
  short* vdst = vtb + ((size_t)bh*64 + tq)*Nc + tch*64 + j*16;
  *(s16x8*)vdst = o0; *(s16x8*)(vdst + 8) = o1;
}

// ============================================================
// Flash attention, 32x32 swapped form (working R5 version, unchanged).
// ============================================================
__global__ __launch_bounds__(256) void attn_kern(const short* __restrict__ qln, const short* __restrict__ kln,
                                                 const short* __restrict__ vtb, short* __restrict__ attnv){
  __shared__ short Ks[128*72];
  __shared__ short Vs[64*136];
  const int tid = threadIdx.x;
  const int bh = blockIdx.x >> 4, qt = blockIdx.x & 15;
  const int b = bh >> 4, h = bh & 15;
  const int w = tid >> 6, lane = tid & 63;
  const int lq = lane & 31, hi = lane >> 5;
  const int qrow = qt*128 + w*32 + lq;

  const short* qp = qln + ((size_t)bh*Nc + qrow)*64 + hi*8;
  s16x8 qf[4];
#pragma unroll
  for (int m = 0; m < 4; ++m) qf[m] = *(const s16x8*)(qp + m*16);

  f32x16 o0 = {0,0,0,0,0,0,0,0,0,0,0,0,0,0,0,0};
  f32x16 o1 = {0,0,0,0,0,0,0,0,0,0,0,0,0,0,0,0};
  float mrun = -INFINITY, l = 0.f;

  const short* kb0 = kln + (size_t)bh*Nc*64;
  const short* vb0 = vtb + (size_t)bh*64*Nc;
  const int vrow = tid >> 2, vq = tid & 3;

  s16x8 kr[4], vr[4];
#pragma unroll
  for (int j = 0; j < 4; ++j){
    kr[j] = *(const s16x8*)(kb0 + (size_t)(tid + j*256)*8);
    vr[j] = *(const s16x8*)(vb0 + (size_t)vrow*Nc + (vq + 4*j)*8);
  }

  for (int kt = 0; kt < 16; ++kt){
#pragma unroll
    for (int j = 0; j < 4; ++j){
      int s = tid + j*256;
      *(s16x8*)&Ks[(s>>3)*72 + (s&7)*8] = kr[j];
      *(s16x8*)&Vs[vrow*136 + (vq + 4*j)*8] = vr[j];
    }
    __syncthreads();
    if (kt + 1 < 16){
      const short* kb = kb0 + (size_t)(kt+1)*128*64;
      const short* vb = vb0 + (kt+1)*128;
#pragma unroll
      for (int j = 0; j < 4; ++j){
        kr[j] = *(const s16x8*)(kb + (size_t)(tid + j*256)*8);
        vr[j] = *(const s16x8*)(vb + (size_t)vrow*Nc + (vq + 4*j)*8);
      }
    }

#pragma unroll
    for (int kc = 0; kc < 4; ++kc){
      f32x16 st = {0,0,0,0,0,0,0,0,0,0,0,0,0,0,0,0};
#pragma unroll
      for (int m = 0; m < 4; ++m){
        s16x8 kf = *(const s16x8*)&Ks[(kc*32 + lq)*72 + m*16 + hi*8];
        st = mfma3216(kf, qf[m], st);
      }
      float cmax = max3f(st[0], st[1], st[2]);
      cmax = max3f(cmax, st[3], st[4]);
      cmax = max3f(cmax, st[5], st[6]);
      cmax = max3f(cmax, st[7], st[8]);
      cmax = max3f(cmax, st[9], st[10]);
      cmax = max3f(cmax, st[11], st[12]);
      cmax = max3f(cmax, st[13], st[14]);
      cmax = fmaxf(cmax, st[15]);
      cmax = fmaxf(cmax, __shfl_xor(cmax, 32));
      if (__any(cmax > mrun + 8.f)){
        float mnew = fmaxf(mrun, cmax);
        float fr = EXP2F(mrun - mnew);
        l *= fr;
#pragma unroll
        for (int r = 0; r < 16; ++r){ o0[r] *= fr; o1[r] *= fr; }
        mrun = mnew;
      }
      float p[16];
#pragma unroll
      for (int r = 0; r < 16; ++r){ p[r] = EXP2F(st[r] - mrun); l += p[r]; }

#pragma unroll
      for (int kh = 0; kh < 2; ++kh){
        int r0 = kh*8;
        unsigned wa = cvtpk(p[r0+0], p[r0+1]);
        unsigned wb = cvtpk(p[r0+4], p[r0+5]);
        unsigned wc2 = cvtpk(p[r0+2], p[r0+3]);
        unsigned wd = cvtpk(p[r0+6], p[r0+7]);
        uint2v s1 = pl32swap(wa, wb);
        uint2v s2 = pl32swap(wc2, wd);
        union { unsigned u[4]; s16x8 v; } pu;
        pu.u[0] = s1[0]; pu.u[1] = s2[0]; pu.u[2] = s1[1]; pu.u[3] = s2[1];
        s16x8 vf0 = *(const s16x8*)&Vs[ lq      *136 + kc*32 + kh*16 + hi*8];
        s16x8 vf1 = *(const s16x8*)&Vs[(32 + lq)*136 + kc*32 + kh*16 + hi*8];
        o0 = mfma3216(vf0, pu.v, o0);
        o1 = mfma3216(vf1, pu.v, o1);
      }
    }
    __syncthreads();
  }

  l += __shfl_xor(l, 32);
  float inv = 1.f / l;
  short* orow = attnv + ((size_t)(b*Nc + qrow))*DIM + h*64;
#pragma unroll
  for (int r = 0; r < 16; r += 2){
    int dv = (r&3) + 8*(r>>2) + 4*hi;
    *(unsigned*)&orow[dv]      = cvtpk(o0[r]*inv, o0[r+1]*inv);
    *(unsigned*)&orow[32 + dv] = cvtpk(o1[r]*inv, o1[r+1]*inv);
  }
}

// ============================================================
// out = LayerNorm(a2 + p2) over 1024, fp32 out
// ============================================================
__global__ __launch_bounds__(256) void final_ln(const short* __restrict__ a2, const short* __restrict__ p2,
                                                float* __restrict__ out){
  __shared__ float red[16];
  int row = blockIdx.x, tid = threadIdx.x;
  size_t base = (size_t)row*DIM + tid*4;
  s16x4 a = *(const s16x4*)(a2 + base);
  s16x4 p = *(const s16x4*)(p2 + base);
  float v[4]; float s = 0.f, sq = 0.f;
#pragma unroll
  for (int i = 0; i < 4; ++i){ v[i] = b2f(a[i]) + b2f(p[i]); s += v[i]; sq += v[i]*v[i]; }
#pragma unroll
  for (int m = 1; m < 64; m <<= 1){ s += __shfl_xor(s, m); sq += __shfl_xor(sq, m); }
  int wv = tid >> 6;
  if ((tid & 63) == 0){ red[wv] = s; red[8 + wv] = sq; }
  __syncthreads();
  if (tid == 0){
    float S = red[0] + red[1] + red[2] + red[3];
    float Q = red[8] + red[9] + red[10] + red[11];
    float mu = S * (1.f/1024.f);
    float var = Q * (1.f/1024.f) - mu*mu;
    red[12] = mu; red[13] = rsqrtf(var + 1e-5f);
  }
  __syncthreads();
  float mu = red[12], inv = red[13];
#pragma unroll
  for (int i = 0; i < 4; ++i) out[base + i] = (v[i] - mu) * inv;
}

// ============================================================
extern "C" void kernel_launch(void* const* d_in, const int* in_sizes, int n_in,
                              void* d_out, int out_size, void* d_ws, size_t ws_size,
                              hipStream_t stream){
  const float* x    = (const float*)d_in[0];
  const float* Wqkv = (const float*)d_in[1];
  const float* W1   = (const float*)d_in[2];
  const float* b1   = (const float*)d_in[3];
  const float* W2   = (const float*)d_in[4];
  const float* b2   = (const float*)d_in[5];
  const float* Wout = (const float*)d_in[6];
  const float* bout = (const float*)d_in[7];
  float* out = (float*)d_out;
  char* ws = (char*)d_ws;

  short* xb    = (short*)(ws + OFF_XB);
  short* wqkvt = (short*)(ws + OFF_WQKVT);
  short* w1t   = (short*)(ws + OFF_W1T);
  short* w2t   = (short*)(ws + OFF_W2T);
  short* woutt = (short*)(ws + OFF_WOUTT);
  short* qkv   = (short*)(ws + OFF_QKV);
  short* qln   = (short*)(ws + OFF_QLN);
  short* kln   = (short*)(ws + OFF_KLN);
  short* vtb   = (short*)(ws + OFF_VT);
  short* attnv = (short*)(ws + OFF_ATTNV);
  short* hbuf  = (short*)(ws + OFF_H);
  short* p2    = (short*)(ws + OFF_P2);
  short* a2    = (short*)(ws + OFF_A2);

  conv_x<<<4096, 256, 0, stream>>>(x, xb);
  transpose_conv<<<(DIM/32)*(D3/32),  256, 0, stream>>>(Wqkv, wqkvt, DIM, D3);
  transpose_conv<<<(DIM/32)*(MLP/32), 256, 0, stream>>>(W1, w1t, DIM, MLP);
  transpose_conv<<<(MLP/32)*(DIM/32), 256, 0, stream>>>(W2, w2t, MLP, DIM);
  transpose_conv<<<(DIM/32)*(DIM/32), 256, 0, stream>>>(Wout, woutt, DIM, DIM);

  gemmDP<128,0><<<(Tc/128)*(D3/256), 512, 0, stream>>>(xb, wqkvt, qkv, nullptr, Tc, D3, DIM);
  ln_reorg<<<64*32, 256, 0, stream>>>(qkv, qln, kln, vtb);
  attn_kern<<<64*16, 256, 0, stream>>>(qln, kln, vtb, attnv);

  gemmDP<256,1><<<(Tc/256)*(MLP/256), 512, 0, stream>>>(xb, w1t, hbuf, b1, Tc, MLP, DIM);
  gemmDP<128,0><<<(Tc/128)*(DIM/256), 512, 0, stream>>>(hbuf, w2t, p2, b2, Tc, DIM, MLP);
  gemmDP<128,0><<<(Tc/128)*(DIM/256), 512, 0, stream>>>(attnv, woutt, a2, bout, Tc, DIM, DIM);

  final_ln<<<Tc, 256, 0, stream>>>(a2, p2, out);
}

// Round 7
// 421.926 us; speedup vs baseline: 1.0263x; 1.0263x over previous
//
#include <hip/hip_runtime.h>

typedef __attribute__((ext_vector_type(8))) short s16x8;
typedef __attribute__((ext_vector_type(4))) short s16x4;
typedef __attribute__((ext_vector_type(4))) float f32x4;
typedef __attribute__((ext_vector_type(16))) float f32x16;
typedef __attribute__((ext_vector_type(2))) unsigned uint2v;

#define DEVINL __device__ __forceinline__

// ---------- bf16 helpers ----------
DEVINL float b2f(short u){ return __uint_as_float(((unsigned)(unsigned short)u) << 16); }
DEVINL short f2bf(float f){
  unsigned u = __float_as_uint(f);
  u += 0x7fffu + ((u >> 16) & 1u);
  return (short)(u >> 16);
}
DEVINL unsigned cvtpk(float lo, float hi){
  unsigned r;
  asm("v_cvt_pk_bf16_f32 %0, %1, %2" : "=v"(r) : "v"(lo), "v"(hi));
  return r;
}
DEVINL float max3f(float a, float b, float c){
  float r; asm("v_max3_f32 %0, %1, %2, %3" : "=v"(r) : "v"(a), "v"(b), "v"(c)); return r;
}

#if __has_builtin(__builtin_amdgcn_exp2f)
#define EXP2F __builtin_amdgcn_exp2f
#else
#define EXP2F exp2f
#endif

// ---------- MFMA wrappers ----------
DEVINL f32x4 mfma32(s16x8 a, s16x8 b, f32x4 c){
  return __builtin_amdgcn_mfma_f32_16x16x32_bf16(a, b, c, 0, 0, 0);
}
DEVINL f32x16 mfma3216(s16x8 a, s16x8 b, f32x16 c){
  return __builtin_amdgcn_mfma_f32_32x32x16_bf16(a, b, c, 0, 0, 0);
}

DEVINL uint2v pl32swap(unsigned a, unsigned b){
#if __has_builtin(__builtin_amdgcn_permlane32_swap)
  return __builtin_amdgcn_permlane32_swap(a, b, false, false);
#else
  asm volatile("v_permlane32_swap_b32 %0, %1" : "+v"(a), "+v"(b));
  uint2v r; r[0] = a; r[1] = b; return r;
#endif
}

// ---------- async global->LDS (width 16) ----------
typedef const unsigned __attribute__((address_space(1)))* gas1;
typedef unsigned __attribute__((address_space(3)))* las3;
DEVINL void gload16(const short* g, short* l){
  __builtin_amdgcn_global_load_lds((gas1)g, (las3)l, 16, 0, 0);
}

// ---------- sync primitives ----------
#define CFENCE asm volatile("" ::: "memory")
#define PBAR  do{ CFENCE; __builtin_amdgcn_sched_barrier(0); __builtin_amdgcn_s_barrier(); \
                  __builtin_amdgcn_sched_barrier(0); CFENCE; }while(0)
#define VMW8 asm volatile("s_waitcnt vmcnt(8)" ::: "memory")
#define VMW4 asm volatile("s_waitcnt vmcnt(4)" ::: "memory")
#define VMW0 asm volatile("s_waitcnt vmcnt(0)" ::: "memory")
#define PRIO1 __builtin_amdgcn_s_setprio(1)
#define PRIO0 __builtin_amdgcn_s_setprio(0)

// ---------- problem constants ----------
static const int Bc   = 4;
static const int Nc   = 2048;
static const int DIM  = 1024;
static const int Tc   = Bc * Nc;      // 8192 tokens
static const int MLP  = 4096;
static const int D3   = 3072;

// ---------- ws layout (bytes) ----------
static const size_t OFF_XB    = 0;
static const size_t OFF_WQKVT = OFF_XB    + 16777216;
static const size_t OFF_W1T   = OFF_WQKVT + 6291456;
static const size_t OFF_W2T   = OFF_W1T   + 8388608;
static const size_t OFF_WOUTT = OFF_W2T   + 8388608;
static const size_t OFF_QKV   = OFF_WOUTT + 2097152;
static const size_t OFF_QLN   = OFF_QKV   + 50331648;
static const size_t OFF_KLN   = OFF_QLN   + 16777216;
static const size_t OFF_VT    = OFF_KLN   + 16777216;
static const size_t OFF_ATTNV = OFF_VT    + 16777216;
static const size_t OFF_H     = OFF_QKV;   // aliases of dead regions
static const size_t OFF_P2    = OFF_KLN;
static const size_t OFF_A2    = OFF_VT;

// ============================================================
// x fp32 -> bf16
// ============================================================
__global__ __launch_bounds__(256) void conv_x(const float* __restrict__ x, short* __restrict__ xb){
  size_t i = ((size_t)blockIdx.x * 256 + threadIdx.x) * 8;
  f32x4 v0 = *(const f32x4*)(x + i);
  f32x4 v1 = *(const f32x4*)(x + i + 4);
  s16x8 o;
#pragma unroll
  for (int j = 0; j < 4; ++j){ o[j] = f2bf(v0[j]); o[4+j] = f2bf(v1[j]); }
  *(s16x8*)(xb + i) = o;
}

// ============================================================
// W[K][N] fp32 -> Wt[N][K] bf16
// ============================================================
__global__ __launch_bounds__(256) void transpose_conv(const float* __restrict__ W, short* __restrict__ Wt,
                                                      int K, int N){
  __shared__ float tile[32][33];
  int ntx = N >> 5;
  int tx = blockIdx.x % ntx, ty = blockIdx.x / ntx;
  int r = threadIdx.x >> 3, c = (threadIdx.x & 7) * 4;
  f32x4 v = *(const f32x4*)(W + (size_t)(ty*32 + r)*N + tx*32 + c);
  tile[r][c] = v[0]; tile[r][c+1] = v[1]; tile[r][c+2] = v[2]; tile[r][c+3] = v[3];
  __syncthreads();
  s16x4 o;
#pragma unroll
  for (int j = 0; j < 4; ++j) o[j] = f2bf(tile[c+j][r]);
  *(s16x4*)(Wt + (size_t)(tx*32 + r)*K + ty*32 + c) = o;
}

// ============================================================
// gemmCF: 128x128 tile, 4 waves (2x2), BK=64, 64KB LDS -> 2 blocks/CU.
// Cross-block overlap (m114) fills barrier/LDS windows of one block with the
// other block's MFMA. 4-phase/2-K-tile pipeline, uniform counted vmcnt(8)
// (stage->read distance = 3 phases). Conflict-free k-group swizzle (R4).
// Epilogue: C tile staged through LDS -> full 256B-segment coalesced stores
// (fixes 2.5x HBM write amplification seen through R6).
// ============================================================
template<int ACT>
__global__ __launch_bounds__(256, 2) void gemmCF(const short* __restrict__ A, const short* __restrict__ Bt,
                                                 short* __restrict__ C, const float* __restrict__ bias,
                                                 int M, int N, int K){
  __shared__ short lds[32768];   // A slots: 0..16383 (4x4096), B slots: 16384..32767

  const int tid = threadIdx.x;
  const int w = tid >> 6, lane = tid & 63;
  const int lr = lane & 15, g = lane >> 4;
  const int wr = w >> 1, wc = w & 1;
  const int NT = K >> 6, NIT = NT >> 1;

  // XCD-chunked bijective swizzle + 8x8 block tiling for L2 locality
  const int nbn = N >> 7;
  const int cpx = gridDim.x >> 3;
  const int bid = (int)blockIdx.x;
  const int sw = (bid & 7)*cpx + (bid >> 3);
  const int nbn8 = nbn >> 3;
  const int T8 = sw >> 6, t64 = sw & 63;
  const int bm = (T8 / nbn8)*8 + (t64 >> 3);
  const int bn = (T8 % nbn8)*8 + (t64 & 7);

  const int l2 = lane >> 2;
  const int gsw = ((lane & 3) - ((lane >> 3) & 3)) & 3;  // inverse swizzle (staging src)
  const int cof = gsw * 8;
  const int qsw8 = ((g + (lr >> 1)) & 3) * 8;            // read swizzle

  const short* ap0 = A  + (size_t)(bm*128 + w*16 + l2)*K + cof;
  const short* bp0 = Bt + (size_t)(bn*128 + w*16 + l2)*K + cof;

  // slot s (0..3): A at lds + s*4096, B at lds + 16384 + s*4096; each 128rows x 32cols
#define STG(soff, src, T_, kk) do{ \
    gload16(src + (size_t)(T_)*64 + (kk)*32,                 lds + (soff) + w*512); \
    gload16(src + (size_t)64*K + (size_t)(T_)*64 + (kk)*32,  lds + (soff) + 2048 + w*512); }while(0)
#define STA(s, T_, kk) STG((s)*4096, ap0, T_, kk)
#define STB(s, T_, kk) STG(16384 + (s)*4096, bp0, T_, kk)
#define LDA(s, mi) (*(const s16x8*)&lds[(s)*4096 + (wr*64 + (mi)*16 + lr)*32 + qsw8])
#define LDB(s, ni) (*(const s16x8*)&lds[16384 + (s)*4096 + (wc*64 + (ni)*16 + lr)*32 + qsw8])

  f32x4 acc[4][4] = {};
#define MM(ai, r) \
  acc[r][0]=mfma32(ai,b0,acc[r][0]); acc[r][1]=mfma32(ai,b1,acc[r][1]); \
  acc[r][2]=mfma32(ai,b2,acc[r][2]); acc[r][3]=mfma32(ai,b3,acc[r][3]);
#define RD(s) s16x8 a0=LDA(s,0),a1=LDA(s,1),a2=LDA(s,2),a3=LDA(s,3), \
                    b0=LDB(s,0),b1=LDB(s,1),b2=LDB(s,2),b3=LDB(s,3);
#define MM16 MM(a0,0) MM(a1,1) MM(a2,2) MM(a3,3)

  // ---- prologue: (0,k0)->s0, (0,k1)->s1, (1,k0)->s2 ; certify (0,k0) ----
  STA(0,0,0); STB(0,0,0);
  STA(1,0,1); STB(1,0,1);
  STA(2,1,0); STB(2,1,0);
  VMW8;
  PBAR;

  for (int i = 0; i < NIT; ++i){
    const int t = i << 1;
    const bool more = (i + 1 < NIT);
    { // p1: read s0=(t,k0); stage (t+1,k1)->s3
      RD(0)
      STA(3, t+1, 1); STB(3, t+1, 1);
      PBAR; PRIO1; MM16 PRIO0;
      VMW8;
      PBAR;
    }
    { // p2: read s1=(t,k1); stage (t+2,k0)->s0
      RD(1)
      if (more){ STA(0, t+2, 0); STB(0, t+2, 0); }
      PBAR; PRIO1; MM16 PRIO0;
      if (more){ VMW8; } else { VMW4; }
      PBAR;
    }
    { // p3: read s2=(t+1,k0); stage (t+2,k1)->s1
      RD(2)
      if (more){ STA(1, t+2, 1); STB(1, t+2, 1); }
      PBAR; PRIO1; MM16 PRIO0;
      if (more){ VMW8; } else { VMW0; }
      PBAR;
    }
    { // p4: read s3=(t+1,k1); stage (t+3,k0)->s2
      RD(3)
      if (more){ STA(2, t+3, 0); STB(2, t+3, 0); }
      PBAR; PRIO1; MM16 PRIO0;
      if (more){ VMW8; }
      PBAR;
    }
  }
#undef MM
#undef RD
#undef MM16
#undef STG
#undef STA
#undef STB
#undef LDA
#undef LDB

  // ---- epilogue: acc -> LDS (bf16) -> coalesced full-segment stores ----
#pragma unroll
  for (int a = 0; a < 4; ++a){
#pragma unroll
    for (int ni = 0; ni < 4; ++ni){
      const int col = wc*64 + ni*16 + lr;
      const float bv = bias ? bias[bn*128 + col] : 0.f;
      f32x4 v = acc[a][ni];
#pragma unroll
      for (int ii = 0; ii < 4; ++ii){
        float val = v[ii] + bv;
        if constexpr (ACT) val = 0.5f*val*(1.f + erff(val*0.70710678118f));
        lds[(wr*64 + a*16 + 4*g + ii)*128 + col] = f2bf(val);
      }
    }
  }
  __syncthreads();
  const size_t crow0 = (size_t)bm * 128;
  const int ch = (tid & 15) * 8;
#pragma unroll
  for (int p = 0; p < 8; ++p){
    const int row = p*16 + (tid >> 4);
    *(s16x8*)&C[(crow0 + row)*N + bn*128 + ch] = *(const s16x8*)&lds[row*128 + ch];
  }
}

// ============================================================
// q/k LayerNorm (d=64) + head-reorg; v -> Vt [bh][d][n]
// ============================================================
__global__ __launch_bounds__(256) void ln_reorg(const short* __restrict__ qkv, short* __restrict__ qln,
                                                short* __restrict__ kln, short* __restrict__ vtb){
  __shared__ short vtile[64*72];
  int bh = blockIdx.x >> 5, tch = blockIdx.x & 31;
  int b = bh >> 4, h = bh & 15;
  int tq = threadIdx.x >> 2, j = threadIdx.x & 3;
  size_t row = (size_t)b*Nc + tch*64 + tq;
  const short* base = qkv + row*D3 + h*64 + j*16;
  size_t orow = ((size_t)bh*Nc + tch*64 + tq)*64 + j*16;

#pragma unroll
  for (int part = 0; part < 2; ++part){
    const short* src = base + part*DIM;
    s16x8 u0 = *(const s16x8*)src;
    s16x8 u1 = *(const s16x8*)(src + 8);
    float f[16]; float s = 0.f, sq = 0.f;
#pragma unroll
    for (int i = 0; i < 8; ++i){ f[i] = b2f(u0[i]); f[8+i] = b2f(u1[i]); }
#pragma unroll
    for (int i = 0; i < 16; ++i){ s += f[i]; sq += f[i]*f[i]; }
    s  += __shfl_xor(s, 1);  s  += __shfl_xor(s, 2);
    sq += __shfl_xor(sq, 1); sq += __shfl_xor(sq, 2);
    float mu = s * (1.f/64.f);
    float var = sq * (1.f/64.f) - mu*mu;
    float inv = rsqrtf(var + 1e-5f) * (part == 0 ? 0.04508422003f : 1.f);
    s16x8 o0, o1;
#pragma unroll
    for (int i = 0; i < 8; ++i){ o0[i] = f2bf((f[i]-mu)*inv); o1[i] = f2bf((f[8+i]-mu)*inv); }
    short* dst = (part == 0 ? qln : kln) + orow;
    *(s16x8*)dst = o0; *(s16x8*)(dst + 8) = o1;
  }

  s16x8 v0 = *(const s16x8*)(base + 2*DIM);
  s16x8 v1 = *(const s16x8*)(base + 2*DIM + 8);
  *(s16x8*)&vtile[tq*72 + j*16]     = v0;
  *(s16x8*)&vtile[tq*72 + j*16 + 8] = v1;
  __syncthreads();
  s16x8 o0, o1;
#pragma unroll
  for (int i = 0; i < 8; ++i){
    o0[i] = vtile[(j*16 + i)*72 + tq];
    o1[i] = vtile[(j*16 + 8 + i)*72 + tq];
  }
  short* vdst = vtb + ((size_t)bh*64 + tq)*Nc + tch*64 + j*16;
  *(s16x8*)vdst = o0; *(s16x8*)(vdst + 8) = o1;
}

// ============================================================
// Flash attention, 32x32 swapped form (working R5/R6 version, unchanged).
// ============================================================
__global__ __launch_bounds__(256) void attn_kern(const short* __restrict__ qln, const short* __restrict__ kln,
                                                 const short* __restrict__ vtb, short* __restrict__ attnv){
  __shared__ short Ks[128*72];
  __shared__ short Vs[64*136];
  const int tid = threadIdx.x;
  const int bh = blockIdx.x >> 4, qt = blockIdx.x & 15;
  const int b = bh >> 4, h = bh & 15;
  const int w = tid >> 6, lane = tid & 63;
  const int lq = lane & 31, hi = lane >> 5;
  const int qrow = qt*128 + w*32 + lq;

  const short* qp = qln + ((size_t)bh*Nc + qrow)*64 + hi*8;
  s16x8 qf[4];
#pragma unroll
  for (int m = 0; m < 4; ++m) qf[m] = *(const s16x8*)(qp + m*16);

  f32x16 o0 = {0,0,0,0,0,0,0,0,0,0,0,0,0,0,0,0};
  f32x16 o1 = {0,0,0,0,0,0,0,0,0,0,0,0,0,0,0,0};
  float mrun = -INFINITY, l = 0.f;

  const short* kb0 = kln + (size_t)bh*Nc*64;
  const short* vb0 = vtb + (size_t)bh*64*Nc;
  const int vrow = tid >> 2, vq = tid & 3;

  s16x8 kr[4], vr[4];
#pragma unroll
  for (int j = 0; j < 4; ++j){
    kr[j] = *(const s16x8*)(kb0 + (size_t)(tid + j*256)*8);
    vr[j] = *(const s16x8*)(vb0 + (size_t)vrow*Nc + (vq + 4*j)*8);
  }

  for (int kt = 0; kt < 16; ++kt){
#pragma unroll
    for (int j = 0; j < 4; ++j){
      int s = tid + j*256;
      *(s16x8*)&Ks[(s>>3)*72 + (s&7)*8] = kr[j];
      *(s16x8*)&Vs[vrow*136 + (vq + 4*j)*8] = vr[j];
    }
    __syncthreads();
    if (kt + 1 < 16){
      const short* kb = kb0 + (size_t)(kt+1)*128*64;
      const short* vb = vb0 + (kt+1)*128;
#pragma unroll
      for (int j = 0; j < 4; ++j){
        kr[j] = *(const s16x8*)(kb + (size_t)(tid + j*256)*8);
        vr[j] = *(const s16x8*)(vb + (size_t)vrow*Nc + (vq + 4*j)*8);
      }
    }

#pragma unroll
    for (int kc = 0; kc < 4; ++kc){
      f32x16 st = {0,0,0,0,0,0,0,0,0,0,0,0,0,0,0,0};
#pragma unroll
      for (int m = 0; m < 4; ++m){
        s16x8 kf = *(const s16x8*)&Ks[(kc*32 + lq)*72 + m*16 + hi*8];
        st = mfma3216(kf, qf[m], st);
      }
      float cmax = max3f(st[0], st[1], st[2]);
      cmax = max3f(cmax, st[3], st[4]);
      cmax = max3f(cmax, st[5], st[6]);
      cmax = max3f(cmax, st[7], st[8]);
      cmax = max3f(cmax, st[9], st[10]);
      cmax = max3f(cmax, st[11], st[12]);
      cmax = max3f(cmax, st[13], st[14]);
      cmax = fmaxf(cmax, st[15]);
      cmax = fmaxf(cmax, __shfl_xor(cmax, 32));
      if (__any(cmax > mrun + 8.f)){
        float mnew = fmaxf(mrun, cmax);
        float fr = EXP2F(mrun - mnew);
        l *= fr;
#pragma unroll
        for (int r = 0; r < 16; ++r){ o0[r] *= fr; o1[r] *= fr; }
        mrun = mnew;
      }
      float p[16];
#pragma unroll
      for (int r = 0; r < 16; ++r){ p[r] = EXP2F(st[r] - mrun); l += p[r]; }

#pragma unroll
      for (int kh = 0; kh < 2; ++kh){
        int r0 = kh*8;
        unsigned wa = cvtpk(p[r0+0], p[r0+1]);
        unsigned wb = cvtpk(p[r0+4], p[r0+5]);
        unsigned wc2 = cvtpk(p[r0+2], p[r0+3]);
        unsigned wd = cvtpk(p[r0+6], p[r0+7]);
        uint2v s1 = pl32swap(wa, wb);
        uint2v s2 = pl32swap(wc2, wd);
        union { unsigned u[4]; s16x8 v; } pu;
        pu.u[0] = s1[0]; pu.u[1] = s2[0]; pu.u[2] = s1[1]; pu.u[3] = s2[1];
        s16x8 vf0 = *(const s16x8*)&Vs[ lq      *136 + kc*32 + kh*16 + hi*8];
        s16x8 vf1 = *(const s16x8*)&Vs[(32 + lq)*136 + kc*32 + kh*16 + hi*8];
        o0 = mfma3216(vf0, pu.v, o0);
        o1 = mfma3216(vf1, pu.v, o1);
      }
    }
    __syncthreads();
  }

  l += __shfl_xor(l, 32);
  float inv = 1.f / l;
  short* orow = attnv + ((size_t)(b*Nc + qrow))*DIM + h*64;
#pragma unroll
  for (int r = 0; r < 16; r += 2){
    int dv = (r&3) + 8*(r>>2) + 4*hi;
    *(unsigned*)&orow[dv]      = cvtpk(o0[r]*inv, o0[r+1]*inv);
    *(unsigned*)&orow[32 + dv] = cvtpk(o1[r]*inv, o1[r+1]*inv);
  }
}

// ============================================================
// out = LayerNorm(a2 + p2) over 1024, fp32 out
// ============================================================
__global__ __launch_bounds__(256) void final_ln(const short* __restrict__ a2, const short* __restrict__ p2,
                                                float* __restrict__ out){
  __shared__ float red[16];
  int row = blockIdx.x, tid = threadIdx.x;
  size_t base = (size_t)row*DIM + tid*4;
  s16x4 a = *(const s16x4*)(a2 + base);
  s16x4 p = *(const s16x4*)(p2 + base);
  float v[4]; float s = 0.f, sq = 0.f;
#pragma unroll
  for (int i = 0; i < 4; ++i){ v[i] = b2f(a[i]) + b2f(p[i]); s += v[i]; sq += v[i]*v[i]; }
#pragma unroll
  for (int m = 1; m < 64; m <<= 1){ s += __shfl_xor(s, m); sq += __shfl_xor(sq, m); }
  int wv = tid >> 6;
  if ((tid & 63) == 0){ red[wv] = s; red[8 + wv] = sq; }
  __syncthreads();
  if (tid == 0){
    float S = red[0] + red[1] + red[2] + red[3];
    float Q = red[8] + red[9] + red[10] + red[11];
    float mu = S * (1.f/1024.f);
    float var = Q * (1.f/1024.f) - mu*mu;
    red[12] = mu; red[13] = rsqrtf(var + 1e-5f);
  }
  __syncthreads();
  float mu = red[12], inv = red[13];
#pragma unroll
  for (int i = 0; i < 4; ++i) out[base + i] = (v[i] - mu) * inv;
}

// ============================================================
extern "C" void kernel_launch(void* const* d_in, const int* in_sizes, int n_in,
                              void* d_out, int out_size, void* d_ws, size_t ws_size,
                              hipStream_t stream){
  const float* x    = (const float*)d_in[0];
  const float* Wqkv = (const float*)d_in[1];
  const float* W1   = (const float*)d_in[2];
  const float* b1   = (const float*)d_in[3];
  const float* W2   = (const float*)d_in[4];
  const float* b2   = (const float*)d_in[5];
  const float* Wout = (const float*)d_in[6];
  const float* bout = (const float*)d_in[7];
  float* out = (float*)d_out;
  char* ws = (char*)d_ws;

  short* xb    = (short*)(ws + OFF_XB);
  short* wqkvt = (short*)(ws + OFF_WQKVT);
  short* w1t   = (short*)(ws + OFF_W1T);
  short* w2t   = (short*)(ws + OFF_W2T);
  short* woutt = (short*)(ws + OFF_WOUTT);
  short* qkv   = (short*)(ws + OFF_QKV);
  short* qln   = (short*)(ws + OFF_QLN);
  short* kln   = (short*)(ws + OFF_KLN);
  short* vtb   = (short*)(ws + OFF_VT);
  short* attnv = (short*)(ws + OFF_ATTNV);
  short* hbuf  = (short*)(ws + OFF_H);
  short* p2    = (short*)(ws + OFF_P2);
  short* a2    = (short*)(ws + OFF_A2);

  conv_x<<<4096, 256, 0, stream>>>(x, xb);
  transpose_conv<<<(DIM/32)*(D3/32),  256, 0, stream>>>(Wqkv, wqkvt, DIM, D3);
  transpose_conv<<<(DIM/32)*(MLP/32), 256, 0, stream>>>(W1, w1t, DIM, MLP);
  transpose_conv<<<(MLP/32)*(DIM/32), 256, 0, stream>>>(W2, w2t, MLP, DIM);
  transpose_conv<<<(DIM/32)*(DIM/32), 256, 0, stream>>>(Wout, woutt, DIM, DIM);

  gemmCF<0><<<(Tc/128)*(D3/128),  256, 0, stream>>>(xb, wqkvt, qkv, nullptr, Tc, D3, DIM);
  ln_reorg<<<64*32, 256, 0, stream>>>(qkv, qln, kln, vtb);
  attn_kern<<<64*16, 256, 0, stream>>>(qln, kln, vtb, attnv);

  gemmCF<1><<<(Tc/128)*(MLP/128), 256, 0, stream>>>(xb, w1t, hbuf, b1, Tc, MLP, DIM);
  gemmCF<0><<<(Tc/128)*(DIM/128), 256, 0, stream>>>(hbuf, w2t, p2, b2, Tc, DIM, MLP);
  gemmCF<0><<<(Tc/128)*(DIM/128), 256, 0, stream>>>(attnv, woutt, a2, bout, Tc, DIM, DIM);

  final_ln<<<Tc, 256, 0, stream>>>(a2, p2, out);
}

// Round 8
// 419.206 us; speedup vs baseline: 1.0330x; 1.0065x over previous
//
#include <hip/hip_runtime.h>

typedef __attribute__((ext_vector_type(8))) short s16x8;
typedef __attribute__((ext_vector_type(4))) short s16x4;
typedef __attribute__((ext_vector_type(4))) float f32x4;
typedef __attribute__((ext_vector_type(16))) float f32x16;
typedef __attribute__((ext_vector_type(2))) unsigned uint2v;

#define DEVINL __device__ __forceinline__

// ---------- bf16 helpers ----------
DEVINL float b2f(short u){ return __uint_as_float(((unsigned)(unsigned short)u) << 16); }
DEVINL short f2bf(float f){
  unsigned u = __float_as_uint(f);
  u += 0x7fffu + ((u >> 16) & 1u);
  return (short)(u >> 16);
}
DEVINL unsigned cvtpk(float lo, float hi){
  unsigned r;
  asm("v_cvt_pk_bf16_f32 %0, %1, %2" : "=v"(r) : "v"(lo), "v"(hi));
  return r;
}
DEVINL float max3f(float a, float b, float c){
  float r; asm("v_max3_f32 %0, %1, %2, %3" : "=v"(r) : "v"(a), "v"(b), "v"(c)); return r;
}

#if __has_builtin(__builtin_amdgcn_exp2f)
#define EXP2F __builtin_amdgcn_exp2f
#else
#define EXP2F exp2f
#endif

// ---------- MFMA wrappers ----------
DEVINL f32x4 mfma32(s16x8 a, s16x8 b, f32x4 c){
  return __builtin_amdgcn_mfma_f32_16x16x32_bf16(a, b, c, 0, 0, 0);
}
DEVINL f32x16 mfma3216(s16x8 a, s16x8 b, f32x16 c){
  return __builtin_amdgcn_mfma_f32_32x32x16_bf16(a, b, c, 0, 0, 0);
}

DEVINL uint2v pl32swap(unsigned a, unsigned b){
#if __has_builtin(__builtin_amdgcn_permlane32_swap)
  return __builtin_amdgcn_permlane32_swap(a, b, false, false);
#else
  asm volatile("v_permlane32_swap_b32 %0, %1" : "+v"(a), "+v"(b));
  uint2v r; r[0] = a; r[1] = b; return r;
#endif
}

// ---------- async global->LDS (width 16) ----------
typedef const unsigned __attribute__((address_space(1)))* gas1;
typedef unsigned __attribute__((address_space(3)))* las3;
DEVINL void gload16(const short* g, short* l){
  __builtin_amdgcn_global_load_lds((gas1)g, (las3)l, 16, 0, 0);
}

// ---------- sync primitives ----------
#define CFENCE asm volatile("" ::: "memory")
#define PBAR  do{ CFENCE; __builtin_amdgcn_sched_barrier(0); __builtin_amdgcn_s_barrier(); \
                  __builtin_amdgcn_sched_barrier(0); CFENCE; }while(0)
#define VMW8 asm volatile("s_waitcnt vmcnt(8)" ::: "memory")
#define VMW4 asm volatile("s_waitcnt vmcnt(4)" ::: "memory")
#define VMW0 asm volatile("s_waitcnt vmcnt(0)" ::: "memory")
#define PRIO1 __builtin_amdgcn_s_setprio(1)
#define PRIO0 __builtin_amdgcn_s_setprio(0)

// ---------- problem constants ----------
static const int Bc   = 4;
static const int Nc   = 2048;
static const int DIM  = 1024;
static const int Tc   = Bc * Nc;      // 8192 tokens
static const int MLP  = 4096;
static const int D3   = 3072;

// ---------- ws layout (bytes) ----------
static const size_t OFF_XB    = 0;
static const size_t OFF_WQKVT = OFF_XB    + 16777216;
static const size_t OFF_W1T   = OFF_WQKVT + 6291456;
static const size_t OFF_W2T   = OFF_W1T   + 8388608;
static const size_t OFF_WOUTT = OFF_W2T   + 8388608;
static const size_t OFF_QKV   = OFF_WOUTT + 2097152;
static const size_t OFF_QLN   = OFF_QKV   + 50331648;
static const size_t OFF_KLN   = OFF_QLN   + 16777216;
static const size_t OFF_VT    = OFF_KLN   + 16777216;
static const size_t OFF_ATTNV = OFF_VT    + 16777216;
static const size_t OFF_H     = OFF_QKV;   // hbuf over dead qkv+qln (after attn)
static const size_t OFF_S2    = OFF_KLN;   // fused MLP2+Wout output over dead kln

// ============================================================
// x fp32 -> bf16
// ============================================================
__global__ __launch_bounds__(256) void conv_x(const float* __restrict__ x, short* __restrict__ xb){
  size_t i = ((size_t)blockIdx.x * 256 + threadIdx.x) * 8;
  f32x4 v0 = *(const f32x4*)(x + i);
  f32x4 v1 = *(const f32x4*)(x + i + 4);
  s16x8 o;
#pragma unroll
  for (int j = 0; j < 4; ++j){ o[j] = f2bf(v0[j]); o[4+j] = f2bf(v1[j]); }
  *(s16x8*)(xb + i) = o;
}

// ============================================================
// W[K][N] fp32 -> Wt[N][K] bf16
// ============================================================
__global__ __launch_bounds__(256) void transpose_conv(const float* __restrict__ W, short* __restrict__ Wt,
                                                      int K, int N){
  __shared__ float tile[32][33];
  int ntx = N >> 5;
  int tx = blockIdx.x % ntx, ty = blockIdx.x / ntx;
  int r = threadIdx.x >> 3, c = (threadIdx.x & 7) * 4;
  f32x4 v = *(const f32x4*)(W + (size_t)(ty*32 + r)*N + tx*32 + c);
  tile[r][c] = v[0]; tile[r][c+1] = v[1]; tile[r][c+2] = v[2]; tile[r][c+3] = v[3];
  __syncthreads();
  s16x4 o;
#pragma unroll
  for (int j = 0; j < 4; ++j) o[j] = f2bf(tile[c+j][r]);
  *(s16x4*)(Wt + (size_t)(tx*32 + r)*K + ty*32 + c) = o;
}

// ============================================================
// gemmCF (R7 structure): 128x128 tile, 4 waves, BK=64, 64KB LDS, 2 blocks/CU,
// counted-vmcnt 4-phase/2-K-tile ring, conflict-free k-group swizzle,
// LDS-staged coalesced epilogue.
// R8: optional FUSED mode — K-range [0,K1) reads A/Bt, [K1,K1+K2) reads A2/Bt2
// (one K=5120 gemm computes hbuf@W2 + attnv@Wout + b2 + bout).
// ============================================================
template<int ACT, int FUSED>
__global__ __launch_bounds__(256, 2) void gemmCF(const short* __restrict__ A, const short* __restrict__ A2,
                                                 const short* __restrict__ Bt, const short* __restrict__ Bt2,
                                                 short* __restrict__ C,
                                                 const float* __restrict__ bias, const float* __restrict__ bias2,
                                                 int M, int N, int K1, int K2){
  __shared__ short lds[32768];   // A slots 0..16383 (4x8KB), B slots 16384..32767

  const int tid = threadIdx.x;
  const int w = tid >> 6, lane = tid & 63;
  const int lr = lane & 15, g = lane >> 4;
  const int wr = w >> 1, wc = w & 1;
  const int NT1 = K1 >> 6;
  const int NT = NT1 + (FUSED ? (K2 >> 6) : 0);
  const int NIT = NT >> 1;

  const int nbn = N >> 7;
  const int cpx = gridDim.x >> 3;
  const int bid = (int)blockIdx.x;
  const int sw = (bid & 7)*cpx + (bid >> 3);
  const int nbn8 = nbn >> 3;
  const int T8 = sw >> 6, t64 = sw & 63;
  const int bm = (T8 / nbn8)*8 + (t64 >> 3);
  const int bn = (T8 % nbn8)*8 + (t64 & 7);

  const int l2 = lane >> 2;
  const int gsw = ((lane & 3) - ((lane >> 3) & 3)) & 3;
  const int cof = gsw * 8;
  const int qsw8 = ((g + (lr >> 1)) & 3) * 8;

  const short* ap0h = A  + (size_t)(bm*128 + w*16 + l2)*K1 + cof;
  const short* bp0h = Bt + (size_t)(bn*128 + w*16 + l2)*K1 + cof;
  const short* ap0a = FUSED ? (A2  + (size_t)(bm*128 + w*16 + l2)*K2 + cof) : nullptr;
  const short* bp0a = FUSED ? (Bt2 + (size_t)(bn*128 + w*16 + l2)*K2 + cof) : nullptr;

  auto stA = [&](int s, int T_, int kk){
    short* d0 = lds + s*4096 + w*512;
    if (FUSED && T_ >= NT1){
      size_t off = (size_t)(T_ - NT1)*64 + kk*32;
      gload16(ap0a + off, d0);
      gload16(ap0a + (size_t)64*K2 + off, d0 + 2048);
    } else {
      size_t off = (size_t)T_*64 + kk*32;
      gload16(ap0h + off, d0);
      gload16(ap0h + (size_t)64*K1 + off, d0 + 2048);
    }
  };
  auto stB = [&](int s, int T_, int kk){
    short* d0 = lds + 16384 + s*4096 + w*512;
    if (FUSED && T_ >= NT1){
      size_t off = (size_t)(T_ - NT1)*64 + kk*32;
      gload16(bp0a + off, d0);
      gload16(bp0a + (size_t)64*K2 + off, d0 + 2048);
    } else {
      size_t off = (size_t)T_*64 + kk*32;
      gload16(bp0h + off, d0);
      gload16(bp0h + (size_t)64*K1 + off, d0 + 2048);
    }
  };

#define LDA(s, mi) (*(const s16x8*)&lds[(s)*4096 + (wr*64 + (mi)*16 + lr)*32 + qsw8])
#define LDB(s, ni) (*(const s16x8*)&lds[16384 + (s)*4096 + (wc*64 + (ni)*16 + lr)*32 + qsw8])

  f32x4 acc[4][4] = {};
#define MM(ai, r) \
  acc[r][0]=mfma32(ai,b0,acc[r][0]); acc[r][1]=mfma32(ai,b1,acc[r][1]); \
  acc[r][2]=mfma32(ai,b2,acc[r][2]); acc[r][3]=mfma32(ai,b3,acc[r][3]);
#define RD(s) s16x8 a0=LDA(s,0),a1=LDA(s,1),a2=LDA(s,2),a3=LDA(s,3), \
                    b0=LDB(s,0),b1=LDB(s,1),b2=LDB(s,2),b3=LDB(s,3);
#define MM16 MM(a0,0) MM(a1,1) MM(a2,2) MM(a3,3)

  // ---- prologue ----
  stA(0,0,0); stB(0,0,0);
  stA(1,0,1); stB(1,0,1);
  stA(2,1,0); stB(2,1,0);
  VMW8;
  PBAR;

  for (int i = 0; i < NIT; ++i){
    const int t = i << 1;
    const bool more = (i + 1 < NIT);
    { // p1: read s0=(t,k0); stage (t+1,k1)->s3
      RD(0)
      stA(3, t+1, 1); stB(3, t+1, 1);
      PBAR; PRIO1; MM16 PRIO0;
      VMW8;
      PBAR;
    }
    { // p2: read s1=(t,k1); stage (t+2,k0)->s0
      RD(1)
      if (more){ stA(0, t+2, 0); stB(0, t+2, 0); }
      PBAR; PRIO1; MM16 PRIO0;
      if (more){ VMW8; } else { VMW4; }
      PBAR;
    }
    { // p3: read s2=(t+1,k0); stage (t+2,k1)->s1
      RD(2)
      if (more){ stA(1, t+2, 1); stB(1, t+2, 1); }
      PBAR; PRIO1; MM16 PRIO0;
      if (more){ VMW8; } else { VMW0; }
      PBAR;
    }
    { // p4: read s3=(t+1,k1); stage (t+3,k0)->s2
      RD(3)
      if (more){ stA(2, t+3, 0); stB(2, t+3, 0); }
      PBAR; PRIO1; MM16 PRIO0;
      if (more){ VMW8; }
      PBAR;
    }
  }
#undef MM
#undef RD
#undef MM16
#undef LDA
#undef LDB

  // ---- epilogue: acc -> LDS (bf16) -> coalesced stores ----
#pragma unroll
  for (int a = 0; a < 4; ++a){
#pragma unroll
    for (int ni = 0; ni < 4; ++ni){
      const int col = wc*64 + ni*16 + lr;
      float bv = bias ? bias[bn*128 + col] : 0.f;
      if (FUSED && bias2) bv += bias2[bn*128 + col];
      f32x4 v = acc[a][ni];
#pragma unroll
      for (int ii = 0; ii < 4; ++ii){
        float val = v[ii] + bv;
        if constexpr (ACT) val = 0.5f*val*(1.f + erff(val*0.70710678118f));
        lds[(wr*64 + a*16 + 4*g + ii)*128 + col] = f2bf(val);
      }
    }
  }
  __syncthreads();
  const size_t crow0 = (size_t)bm * 128;
  const int ch = (tid & 15) * 8;
#pragma unroll
  for (int p = 0; p < 8; ++p){
    const int row = p*16 + (tid >> 4);
    *(s16x8*)&C[(crow0 + row)*N + bn*128 + ch] = *(const s16x8*)&lds[row*128 + ch];
  }
}

// ============================================================
// q/k LayerNorm (d=64) + head-reorg; v -> Vt [bh][d][n]
// ============================================================
__global__ __launch_bounds__(256) void ln_reorg(const short* __restrict__ qkv, short* __restrict__ qln,
                                                short* __restrict__ kln, short* __restrict__ vtb){
  __shared__ short vtile[64*72];
  int bh = blockIdx.x >> 5, tch = blockIdx.x & 31;
  int b = bh >> 4, h = bh & 15;
  int tq = threadIdx.x >> 2, j = threadIdx.x & 3;
  size_t row = (size_t)b*Nc + tch*64 + tq;
  const short* base = qkv + row*D3 + h*64 + j*16;
  size_t orow = ((size_t)bh*Nc + tch*64 + tq)*64 + j*16;

#pragma unroll
  for (int part = 0; part < 2; ++part){
    const short* src = base + part*DIM;
    s16x8 u0 = *(const s16x8*)src;
    s16x8 u1 = *(const s16x8*)(src + 8);
    float f[16]; float s = 0.f, sq = 0.f;
#pragma unroll
    for (int i = 0; i < 8; ++i){ f[i] = b2f(u0[i]); f[8+i] = b2f(u1[i]); }
#pragma unroll
    for (int i = 0; i < 16; ++i){ s += f[i]; sq += f[i]*f[i]; }
    s  += __shfl_xor(s, 1);  s  += __shfl_xor(s, 2);
    sq += __shfl_xor(sq, 1); sq += __shfl_xor(sq, 2);
    float mu = s * (1.f/64.f);
    float var = sq * (1.f/64.f) - mu*mu;
    float inv = rsqrtf(var + 1e-5f) * (part == 0 ? 0.04508422003f : 1.f);
    s16x8 o0, o1;
#pragma unroll
    for (int i = 0; i < 8; ++i){ o0[i] = f2bf((f[i]-mu)*inv); o1[i] = f2bf((f[8+i]-mu)*inv); }
    short* dst = (part == 0 ? qln : kln) + orow;
    *(s16x8*)dst = o0; *(s16x8*)(dst + 8) = o1;
  }

  s16x8 v0 = *(const s16x8*)(base + 2*DIM);
  s16x8 v1 = *(const s16x8*)(base + 2*DIM + 8);
  *(s16x8*)&vtile[tq*72 + j*16]     = v0;
  *(s16x8*)&vtile[tq*72 + j*16 + 8] = v1;
  __syncthreads();
  s16x8 o0, o1;
#pragma unroll
  for (int i = 0; i < 8; ++i){
    o0[i] = vtile[(j*16 + i)*72 + tq];
    o1[i] = vtile[(j*16 + 8 + i)*72 + tq];
  }
  short* vdst = vtb + ((size_t)bh*64 + tq)*Nc + tch*64 + j*16;
  *(s16x8*)vdst = o0; *(s16x8*)(vdst + 8) = o1;
}

// ============================================================
// Flash attention R8: KVBLK=64 double-buffered LDS (ONE barrier per kt),
// T14 reg-prefetch, fused 2x32-key processing: 8 QK MFMAs clustered, one
// combined max/defer-branch per 64 keys, then both PV clusters.
// ============================================================
__global__ __launch_bounds__(256) void attn_kern(const short* __restrict__ qln, const short* __restrict__ kln,
                                                 const short* __restrict__ vtb, short* __restrict__ attnv){
  __shared__ short Ks[2][64*72];   // [buf][key][d64 +8]
  __shared__ short Vs[2][64*72];   // [buf][dv][key64 +8]
  const int tid = threadIdx.x;
  const int bh = blockIdx.x >> 4, qt = blockIdx.x & 15;
  const int b = bh >> 4, h = bh & 15;
  const int w = tid >> 6, lane = tid & 63;
  const int lq = lane & 31, hi = lane >> 5;
  const int qrow = qt*128 + w*32 + lq;

  const short* qp = qln + ((size_t)bh*Nc + qrow)*64 + hi*8;
  s16x8 qf[4];
#pragma unroll
  for (int m = 0; m < 4; ++m) qf[m] = *(const s16x8*)(qp + m*16);

  f32x16 o0 = {0,0,0,0,0,0,0,0,0,0,0,0,0,0,0,0};
  f32x16 o1 = {0,0,0,0,0,0,0,0,0,0,0,0,0,0,0,0};
  float mrun = -INFINITY, l = 0.f;

  const int sr = tid >> 3;            // 0..31
  const int sc = (tid & 7) * 8;       // 0,8,..,56
  const short* kb0 = kln + (size_t)bh*Nc*64;
  const short* vb0 = vtb + (size_t)bh*64*Nc;

  s16x8 kr0, kr1, vr0, vr1;
  {
    kr0 = *(const s16x8*)(kb0 + (size_t)sr*64 + sc);
    kr1 = *(const s16x8*)(kb0 + (size_t)(32 + sr)*64 + sc);
    vr0 = *(const s16x8*)(vb0 + (size_t)sr*Nc + sc);
    vr1 = *(const s16x8*)(vb0 + (size_t)(32 + sr)*Nc + sc);
  }

  for (int kt = 0; kt < 32; ++kt){
    const int cur = kt & 1;
    *(s16x8*)&Ks[cur][sr*72 + sc]        = kr0;
    *(s16x8*)&Ks[cur][(32 + sr)*72 + sc] = kr1;
    *(s16x8*)&Vs[cur][sr*72 + sc]        = vr0;
    *(s16x8*)&Vs[cur][(32 + sr)*72 + sc] = vr1;
    __syncthreads();
    if (kt + 1 < 32){   // T14: prefetch next tile; hides under this tile's compute
      const short* kb = kb0 + (size_t)(kt+1)*64*64;
      const short* vb = vb0 + (kt+1)*64;
      kr0 = *(const s16x8*)(kb + (size_t)sr*64 + sc);
      kr1 = *(const s16x8*)(kb + (size_t)(32 + sr)*64 + sc);
      vr0 = *(const s16x8*)(vb + (size_t)sr*Nc + sc);
      vr1 = *(const s16x8*)(vb + (size_t)(32 + sr)*Nc + sc);
    }

    // ---- both 32-key QK^T clusters (independent; 8 MFMAs) ----
    f32x16 st0 = {0,0,0,0,0,0,0,0,0,0,0,0,0,0,0,0};
    f32x16 st1 = {0,0,0,0,0,0,0,0,0,0,0,0,0,0,0,0};
#pragma unroll
    for (int m = 0; m < 4; ++m){
      s16x8 kf0 = *(const s16x8*)&Ks[cur][ lq      *72 + m*16 + hi*8];
      s16x8 kf1 = *(const s16x8*)&Ks[cur][(32 + lq)*72 + m*16 + hi*8];
      st0 = mfma3216(kf0, qf[m], st0);
      st1 = mfma3216(kf1, qf[m], st1);
    }

    // ---- combined max over 32 values + one defer-branch per 64 keys ----
    float cmax = max3f(st0[0], st0[1], st0[2]);
    cmax = max3f(cmax, st0[3], st0[4]);   cmax = max3f(cmax, st0[5], st0[6]);
    cmax = max3f(cmax, st0[7], st0[8]);   cmax = max3f(cmax, st0[9], st0[10]);
    cmax = max3f(cmax, st0[11], st0[12]); cmax = max3f(cmax, st0[13], st0[14]);
    cmax = max3f(cmax, st0[15], st1[0]);  cmax = max3f(cmax, st1[1], st1[2]);
    cmax = max3f(cmax, st1[3], st1[4]);   cmax = max3f(cmax, st1[5], st1[6]);
    cmax = max3f(cmax, st1[7], st1[8]);   cmax = max3f(cmax, st1[9], st1[10]);
    cmax = max3f(cmax, st1[11], st1[12]); cmax = max3f(cmax, st1[13], st1[14]);
    cmax = fmaxf(cmax, st1[15]);
    cmax = fmaxf(cmax, __shfl_xor(cmax, 32));
    if (__any(cmax > mrun + 8.f)){        // defer-max (T13)
      float mnew = fmaxf(mrun, cmax);
      float fr = EXP2F(mrun - mnew);
      l *= fr;
#pragma unroll
      for (int r = 0; r < 16; ++r){ o0[r] *= fr; o1[r] *= fr; }
      mrun = mnew;
    }
    float p0[16], p1[16];
#pragma unroll
    for (int r = 0; r < 16; ++r){
      p0[r] = EXP2F(st0[r] - mrun); l += p0[r];
      p1[r] = EXP2F(st1[r] - mrun); l += p1[r];
    }

    // ---- PV for both key halves ----
#pragma unroll
    for (int kc = 0; kc < 2; ++kc){
      const float* p = kc ? p1 : p0;
#pragma unroll
      for (int kh = 0; kh < 2; ++kh){
        int r0 = kh*8;
        unsigned wa = cvtpk(p[r0+0], p[r0+1]);
        unsigned wb = cvtpk(p[r0+4], p[r0+5]);
        unsigned wc2 = cvtpk(p[r0+2], p[r0+3]);
        unsigned wd = cvtpk(p[r0+6], p[r0+7]);
        uint2v s1 = pl32swap(wa, wb);
        uint2v s2 = pl32swap(wc2, wd);
        union { unsigned u[4]; s16x8 v; } pu;
        pu.u[0] = s1[0]; pu.u[1] = s2[0]; pu.u[2] = s1[1]; pu.u[3] = s2[1];
        s16x8 vf0 = *(const s16x8*)&Vs[cur][ lq      *72 + kc*32 + kh*16 + hi*8];
        s16x8 vf1 = *(const s16x8*)&Vs[cur][(32 + lq)*72 + kc*32 + kh*16 + hi*8];
        o0 = mfma3216(vf0, pu.v, o0);
        o1 = mfma3216(vf1, pu.v, o1);
      }
    }
    // no trailing barrier: next iteration writes buf cur^1, whose readers all
    // passed this iteration's barrier (rendezvous argument; 1 barrier per kt)
  }

  l += __shfl_xor(l, 32);
  float inv = 1.f / l;
  short* orow = attnv + ((size_t)(b*Nc + qrow))*DIM + h*64;
#pragma unroll
  for (int r = 0; r < 16; r += 2){
    int dv = (r&3) + 8*(r>>2) + 4*hi;
    *(unsigned*)&orow[dv]      = cvtpk(o0[r]*inv, o0[r+1]*inv);
    *(unsigned*)&orow[32 + dv] = cvtpk(o1[r]*inv, o1[r+1]*inv);
  }
}

// ============================================================
// out = LayerNorm(s2) over 1024, fp32 out
// ============================================================
__global__ __launch_bounds__(256) void final_ln(const short* __restrict__ s2, float* __restrict__ out){
  __shared__ float red[16];
  int row = blockIdx.x, tid = threadIdx.x;
  size_t base = (size_t)row*DIM + tid*4;
  s16x4 a = *(const s16x4*)(s2 + base);
  float v[4]; float s = 0.f, sq = 0.f;
#pragma unroll
  for (int i = 0; i < 4; ++i){ v[i] = b2f(a[i]); s += v[i]; sq += v[i]*v[i]; }
#pragma unroll
  for (int m = 1; m < 64; m <<= 1){ s += __shfl_xor(s, m); sq += __shfl_xor(sq, m); }
  int wv = tid >> 6;
  if ((tid & 63) == 0){ red[wv] = s; red[8 + wv] = sq; }
  __syncthreads();
  if (tid == 0){
    float S = red[0] + red[1] + red[2] + red[3];
    float Q = red[8] + red[9] + red[10] + red[11];
    float mu = S * (1.f/1024.f);
    float var = Q * (1.f/1024.f) - mu*mu;
    red[12] = mu; red[13] = rsqrtf(var + 1e-5f);
  }
  __syncthreads();
  float mu = red[12], inv = red[13];
#pragma unroll
  for (int i = 0; i < 4; ++i) out[base + i] = (v[i] - mu) * inv;
}

// ============================================================
extern "C" void kernel_launch(void* const* d_in, const int* in_sizes, int n_in,
                              void* d_out, int out_size, void* d_ws, size_t ws_size,
                              hipStream_t stream){
  const float* x    = (const float*)d_in[0];
  const float* Wqkv = (const float*)d_in[1];
  const float* W1   = (const float*)d_in[2];
  const float* b1   = (const float*)d_in[3];
  const float* W2   = (const float*)d_in[4];
  const float* b2   = (const float*)d_in[5];
  const float* Wout = (const float*)d_in[6];
  const float* bout = (const float*)d_in[7];
  float* out = (float*)d_out;
  char* ws = (char*)d_ws;

  short* xb    = (short*)(ws + OFF_XB);
  short* wqkvt = (short*)(ws + OFF_WQKVT);
  short* w1t   = (short*)(ws + OFF_W1T);
  short* w2t   = (short*)(ws + OFF_W2T);
  short* woutt = (short*)(ws + OFF_WOUTT);
  short* qkv   = (short*)(ws + OFF_QKV);
  short* qln   = (short*)(ws + OFF_QLN);
  short* kln   = (short*)(ws + OFF_KLN);
  short* vtb   = (short*)(ws + OFF_VT);
  short* attnv = (short*)(ws + OFF_ATTNV);
  short* hbuf  = (short*)(ws + OFF_H);
  short* s2    = (short*)(ws + OFF_S2);

  conv_x<<<4096, 256, 0, stream>>>(x, xb);
  transpose_conv<<<(DIM/32)*(D3/32),  256, 0, stream>>>(Wqkv, wqkvt, DIM, D3);
  transpose_conv<<<(DIM/32)*(MLP/32), 256, 0, stream>>>(W1, w1t, DIM, MLP);
  transpose_conv<<<(MLP/32)*(DIM/32), 256, 0, stream>>>(W2, w2t, MLP, DIM);
  transpose_conv<<<(DIM/32)*(DIM/32), 256, 0, stream>>>(Wout, woutt, DIM, DIM);

  gemmCF<0,0><<<(Tc/128)*(D3/128), 256, 0, stream>>>(xb, xb, wqkvt, wqkvt, qkv,
                                                     nullptr, nullptr, Tc, D3, DIM, DIM);
  ln_reorg<<<64*32, 256, 0, stream>>>(qkv, qln, kln, vtb);
  attn_kern<<<64*16, 256, 0, stream>>>(qln, kln, vtb, attnv);

  gemmCF<1,0><<<(Tc/128)*(MLP/128), 256, 0, stream>>>(xb, xb, w1t, w1t, hbuf,
                                                      b1, nullptr, Tc, MLP, DIM, DIM);
  // fused: s2 = hbuf@W2 + attnv@Wout + b2 + bout   (K = 4096 + 1024)
  gemmCF<0,1><<<(Tc/128)*(DIM/128), 256, 0, stream>>>(hbuf, attnv, w2t, woutt, s2,
                                                      b2, bout, Tc, DIM, MLP, DIM);

  final_ln<<<Tc, 256, 0, stream>>>(s2, out);
}